// Round 9
// baseline (254.534 us; speedup 1.0000x reference)
//
#include <hip/hip_runtime.h>
#include <hip/hip_bf16.h>

// Problem constants (SparseMoE: D=512, H=2048, O=512, E=8, K=2, CF=1.0)
#define NTOK 16384
#define DDIM 512
#define HDIM 2048
#define ODIM 512
#define NE 8
#define CAP 2048   // max(int(N/E*CF), 4) = 2048

typedef __attribute__((ext_vector_type(8))) short short8v;
typedef __attribute__((ext_vector_type(4))) short short4v;
typedef __attribute__((ext_vector_type(8))) unsigned short ushort8v;
typedef __attribute__((ext_vector_type(4))) float f32x4;

static __device__ __forceinline__ unsigned short f2bf(float f) {
  __hip_bfloat16 h = __float2bfloat16(f);
  return __builtin_bit_cast(unsigned short, h);
}

// async global->LDS, 16B per lane; LDS dest = wave-uniform base + lane*16
#define GLOAD_LDS16(gp, lp)                                               \
  __builtin_amdgcn_global_load_lds(                                       \
      (const __attribute__((address_space(1))) void*)(gp),                \
      (__attribute__((address_space(3))) void*)(lp), 16, 0, 0)

// ---------------- fused prep: transpose w1, transpose w2, gating
__device__ __forceinline__ void transpose_block(const float* __restrict__ src,
                                                __hip_bfloat16* __restrict__ dst,
                                                int R, int C, int b) {
  __shared__ float tile[32][33];
  int nx = C >> 5, ny = R >> 5;
  int x = b % nx, y = (b / nx) % ny, e = b / (nx * ny);
  size_t base = (size_t)e * R * C;
  int c0 = x * 32, r0 = y * 32;
  int tx = threadIdx.x & 31, ty = threadIdx.x >> 5;
#pragma unroll
  for (int i = 0; i < 32; i += 8)
    tile[ty + i][tx] = src[base + (size_t)(r0 + ty + i) * C + c0 + tx];
  __syncthreads();
#pragma unroll
  for (int i = 0; i < 32; i += 8)
    dst[base + (size_t)(c0 + ty + i) * R + r0 + tx] = __float2bfloat16(tile[tx][ty + i]);
}

__global__ void k_prep(const float* __restrict__ x, const float* __restrict__ gw,
                       const float* __restrict__ gb, const float* __restrict__ w1,
                       __hip_bfloat16* __restrict__ w1t, const float* __restrict__ w2,
                       __hip_bfloat16* __restrict__ w2t, float* __restrict__ gate_probs,
                       int2* __restrict__ tk_e, float2* __restrict__ tk_w) {
  int b = blockIdx.x;
  if (b < 8192) { transpose_block(w1, w1t, DDIM, HDIM, b); return; }
  if (b < 16384) { transpose_block(w2, w2t, HDIM, ODIM, b - 8192); return; }
  b -= 16384;
  __shared__ float gws[DDIM * 9];
  int tid = threadIdx.x;
  for (int i = tid; i < DDIM * NE; i += 256) {
    int d = i >> 3, e = i & 7;
    gws[d * 9 + e] = gw[i];
  }
  __syncthreads();
  int wid = tid >> 6, lane = tid & 63;
  int t = b * 4 + wid;
  const float* xr = x + (size_t)t * DDIM;
  float acc[NE] = {0.f, 0.f, 0.f, 0.f, 0.f, 0.f, 0.f, 0.f};
#pragma unroll
  for (int j = 0; j < 8; ++j) {
    float xv = xr[lane + 64 * j];
    const float* g = &gws[(lane + 64 * j) * 9];
#pragma unroll
    for (int e = 0; e < NE; ++e) acc[e] += xv * g[e];
  }
#pragma unroll
  for (int e = 0; e < NE; ++e) {
#pragma unroll
    for (int off = 32; off > 0; off >>= 1) acc[e] += __shfl_xor(acc[e], off, 64);
  }
  if (lane == 0) {
    float p[NE];
    float m = -1e30f;
#pragma unroll
    for (int e = 0; e < NE; ++e) { p[e] = acc[e] + gb[e]; m = fmaxf(m, p[e]); }
    float s = 0.f;
#pragma unroll
    for (int e = 0; e < NE; ++e) { p[e] = expf(p[e] - m); s += p[e]; }
    float inv = 1.f / s;
#pragma unroll
    for (int e = 0; e < NE; ++e) { p[e] *= inv; gate_probs[(size_t)t * NE + e] = p[e]; }
    int i1 = 0; float p1 = p[0];
#pragma unroll
    for (int e = 1; e < NE; ++e) if (p[e] > p1) { p1 = p[e]; i1 = e; }
    int i2 = -1; float p2 = -1e30f;
#pragma unroll
    for (int e = 0; e < NE; ++e) if (e != i1 && p[e] > p2) { p2 = p[e]; i2 = e; }
    float wsum = p1 + p2;
    tk_e[t] = make_int2(i1, i2);
    tk_w[t] = make_float2(p1 / wsum, p2 / wsum);
  }
}

// ---------------- dispatch: per-expert FCFS capacity assignment (block scan)
// Emits expert_tokens (slot -> token id) and slot_w (slot -> gate weight).
__global__ void k_dispatch(const int2* __restrict__ tk_e, const float2* __restrict__ tk_w,
                           int* __restrict__ expert_tokens, float* __restrict__ slot_w) {
  int e = blockIdx.x;
  int tid = threadIdx.x;
  int lane = tid & 63, w = tid >> 6;   // 16 waves
  __shared__ int wave_cnt[16];
  int base = 0;
  for (int chunk = 0; chunk < NTOK / 1024; ++chunk) {
    int t = chunk * 1024 + tid;
    int2 te = tk_e[t];
    float2 wv = tk_w[t];
    int k = (te.x == e) ? 0 : ((te.y == e) ? 1 : -1);
    bool flag = (k >= 0);
    unsigned long long m = __ballot(flag);
    int pre = __popcll(m & ((1ull << lane) - 1ull));
    __syncthreads();
    if (lane == 0) wave_cnt[w] = __popcll(m);
    __syncthreads();
    int off = 0, total = 0;
#pragma unroll
    for (int i = 0; i < 16; ++i) {
      off += (i < w) ? wave_cnt[i] : 0;
      total += wave_cnt[i];
    }
    int rank = base + off + pre;
    if (flag && rank < CAP) {
      expert_tokens[e * CAP + rank] = t;
      slot_w[e * CAP + rank] = (k == 0) ? wv.x : wv.y;
    }
    base += total;
  }
  int nvalid = base < CAP ? base : CAP;
  for (int s = nvalid + tid; s < CAP; s += 1024) {
    expert_tokens[e * CAP + s] = 0;  // padded: weight 0 -> contributes nothing
    slot_w[e * CAP + s] = 0.f;
  }
}

// ---------------- gather: xg[e][c][:] = bf16(x[expert_tokens[e*CAP+c]][:])
__global__ void k_gather(const float* __restrict__ x,
                         const int* __restrict__ expert_tokens,
                         __hip_bfloat16* __restrict__ xg) {
  int tid = threadIdx.x, wid = tid >> 6, lane = tid & 63;
  int slot = blockIdx.x * 4 + wid;  // 0..E*CAP-1
  int tok = expert_tokens[slot];
  const float4* src = reinterpret_cast<const float4*>(x + (size_t)tok * DDIM) + lane * 2;
  float4 u = src[0], v = src[1];
  ushort8v o;
  o[0] = f2bf(u.x); o[1] = f2bf(u.y); o[2] = f2bf(u.z); o[3] = f2bf(u.w);
  o[4] = f2bf(v.x); o[5] = f2bf(v.y); o[6] = f2bf(v.z); o[7] = f2bf(v.w);
  *reinterpret_cast<ushort8v*>(xg + (size_t)slot * DDIM + lane * 8) = o;
}

// sigmoid-form tanh-GELU: |err vs exact erf-gelu| < ~1e-3, safe for bf16 out
static __device__ __forceinline__ float gelu_fast(float v) {
  float z = 1.5957691216057308f * (v + 0.044715f * v * v * v);
  return v / (1.f + __expf(-z));
}

// ---------------- pipelined GEMM (best-measured config, r4/r5: 62 us/GEMM):
// 128x128 tile, BK=32, 3 LDS buffers, register ping-pong fragments.
// A = weights (E, M, K); B = tokens (E, CAP, K); C = (E, CAP, M).
// FUSE=true (GEMM2): epilogue scatters weighted rows into comb via
// atomicAdd (<=2 adds per address -> IEEE-commutative -> deterministic).
template <int K, int M, bool GELU, bool FUSE, typename OutT>
__global__ __launch_bounds__(256, 3) void k_gemm(
    const __hip_bfloat16* __restrict__ A, const __hip_bfloat16* __restrict__ B,
    const float* __restrict__ bias, OutT* __restrict__ C,
    const int* __restrict__ expert_tokens, const float* __restrict__ slot_w,
    float* __restrict__ comb) {
  __shared__ char lds[3][16384];  // [buf][ A:8KB | B:8KB ], 48 KB total
  // XCD-aware bijective remap (grid total is a multiple of 8)
  int gx = gridDim.x, gy = gridDim.y;
  int lin = (blockIdx.z * gy + blockIdx.y) * gx + blockIdx.x;
  int total = gx * gy * (int)gridDim.z;
  int cpx = total >> 3;
  lin = (lin & 7) * cpx + (lin >> 3);
  int gxy = gx * gy;
  int e = lin / gxy;
  int rem = lin - e * gxy;
  int mt = rem / gx, nt = rem - mt * gx;

  const int m0 = mt * 128, n0 = nt * 128;
  const int tid = threadIdx.x;
  const int lane = tid & 63, wid = tid >> 6;
  const int wr = wid >> 1, wc = wid & 1;
  const int lrow = lane & 15, kseg = lane >> 4;

  const int r0 = tid >> 2;                     // staging row 0..63
  const int sc = (tid & 3) ^ ((r0 >> 1) & 3);  // inverse-swizzled source k16
  const int cb0 = (tid & 192) * 16;            // wave-uniform LDS byte base
  const int cb1 = 4096 + cb0;
  const __hip_bfloat16* Ab = A + ((size_t)e * M + m0) * K;
  const __hip_bfloat16* Bb = B + ((size_t)e * CAP + n0) * K;

#define STAGE(buf, kk)                                                         \
  do {                                                                         \
    GLOAD_LDS16(Ab + (size_t)r0 * K + (kk) + sc * 8, lds[buf] + cb0);          \
    GLOAD_LDS16(Ab + (size_t)(r0 + 64) * K + (kk) + sc * 8, lds[buf] + cb1);   \
    GLOAD_LDS16(Bb + (size_t)r0 * K + (kk) + sc * 8, lds[buf] + 8192 + cb0);   \
    GLOAD_LDS16(Bb + (size_t)(r0 + 64) * K + (kk) + sc * 8, lds[buf] + 8192 + cb1); \
  } while (0)

#define READF(fa, fb, bi)                                                      \
  do {                                                                         \
    const char* AsB_ = lds[bi];                                                \
    const char* BsB_ = lds[bi] + 8192;                                         \
    _Pragma("unroll")                                                          \
    for (int mm = 0; mm < 4; ++mm) {                                           \
      int rr = wr * 64 + mm * 16 + lrow;                                       \
      int ks = kseg ^ ((rr >> 1) & 3);                                         \
      fa[mm] = *reinterpret_cast<const short8v*>(AsB_ + rr * 64 + ks * 16);    \
    }                                                                          \
    _Pragma("unroll")                                                          \
    for (int nn = 0; nn < 4; ++nn) {                                           \
      int rr = wc * 64 + nn * 16 + lrow;                                       \
      int ks = kseg ^ ((rr >> 1) & 3);                                         \
      fb[nn] = *reinterpret_cast<const short8v*>(BsB_ + rr * 64 + ks * 16);    \
    }                                                                          \
  } while (0)

#define MFMA16(fa, fb)                                                         \
  do {                                                                         \
    __builtin_amdgcn_s_setprio(1);                                             \
    _Pragma("unroll")                                                          \
    for (int mm = 0; mm < 4; ++mm)                                             \
      _Pragma("unroll")                                                        \
      for (int nn = 0; nn < 4; ++nn)                                           \
        acc[mm][nn] = __builtin_amdgcn_mfma_f32_16x16x32_bf16(                 \
            fa[mm], fb[nn], acc[mm][nn], 0, 0, 0);                             \
    __builtin_amdgcn_s_setprio(0);                                             \
  } while (0)

#define LGKM0_FENCE()                                                          \
  do {                                                                         \
    asm volatile("s_waitcnt lgkmcnt(0)" ::: "memory");                         \
    __builtin_amdgcn_sched_barrier(0);                                         \
  } while (0)

  f32x4 acc[4][4] = {};
  short8v pa[4], pb[4], qa[4], qb[4];  // ping / pong fragment sets
  const int T = K >> 5;                // K-tiles: 16 (GEMM1) or 64 (GEMM2)

  STAGE(0, 0);
  STAGE(1, 32);
  STAGE(2, 64);
  asm volatile("s_waitcnt vmcnt(8)" ::: "memory");  // tile 0 resident
  __builtin_amdgcn_s_barrier();
  READF(pa, pb, 0);
  LGKM0_FENCE();

  int bt = 0;  // t % 3
  for (int t = 0; t < T; t += 2) {
    int b1 = (bt == 2) ? 0 : bt + 1;  // (t+1) % 3
    int b2 = (b1 == 2) ? 0 : b1 + 1;  // (t+2) % 3
    // ---- even step: make tile t+1 visible, read->pong, MFMA ping
    if (t + 2 < T) asm volatile("s_waitcnt vmcnt(4)" ::: "memory");
    else           asm volatile("s_waitcnt vmcnt(0)" ::: "memory");
    __builtin_amdgcn_s_barrier();
    READF(qa, qb, b1);
    if (t + 3 < T) STAGE(bt, (t + 3) * 32);
    __builtin_amdgcn_sched_barrier(0);  // reads+stage issue before MFMA
    MFMA16(pa, pb);
    LGKM0_FENCE();                      // pong landed; fence next MFMA
    // ---- odd step: make tile t+2 visible, read->ping, MFMA pong
    if (t + 2 < T) {
      if (t + 3 < T) asm volatile("s_waitcnt vmcnt(4)" ::: "memory");
      else           asm volatile("s_waitcnt vmcnt(0)" ::: "memory");
      __builtin_amdgcn_s_barrier();
      READF(pa, pb, b2);
      if (t + 4 < T) STAGE(b1, (t + 4) * 32);
      __builtin_amdgcn_sched_barrier(0);
    }
    MFMA16(qa, qb);
    LGKM0_FENCE();
    bt = b2;
  }
#undef STAGE
#undef READF
#undef MFMA16
#undef LGKM0_FENCE

  if constexpr (FUSE) {
    // fused-combine epilogue: comb[tok] += (acc + bias) * slot_w
    int tokslot[4]; float sw[4];
#pragma unroll
    for (int nn = 0; nn < 4; ++nn) {
      int ts = e * CAP + n0 + wc * 64 + nn * 16 + lrow;
      tokslot[nn] = expert_tokens[ts];
      sw[nn] = slot_w[ts];
    }
#pragma unroll
    for (int mm = 0; mm < 4; ++mm) {
      int mrow = m0 + wr * 64 + mm * 16 + kseg * 4;
      float4 bv = *reinterpret_cast<const float4*>(&bias[e * M + mrow]);
#pragma unroll
      for (int nn = 0; nn < 4; ++nn) {
        float* cp = comb + (size_t)tokslot[nn] * ODIM + mrow;
        atomicAdd(cp + 0, (acc[mm][nn][0] + bv.x) * sw[nn]);
        atomicAdd(cp + 1, (acc[mm][nn][1] + bv.y) * sw[nn]);
        atomicAdd(cp + 2, (acc[mm][nn][2] + bv.z) * sw[nn]);
        atomicAdd(cp + 3, (acc[mm][nn][3] + bv.w) * sw[nn]);
      }
    }
  } else {
    // epilogue: lane holds 4 consecutive output-features at one token
#pragma unroll
    for (int mm = 0; mm < 4; ++mm) {
      int mrow = m0 + wr * 64 + mm * 16 + kseg * 4;
      float4 bv = *reinterpret_cast<const float4*>(&bias[e * M + mrow]);
#pragma unroll
      for (int nn = 0; nn < 4; ++nn) {
        int token = n0 + wc * 64 + nn * 16 + lrow;
        float v0 = acc[mm][nn][0] + bv.x;
        float v1 = acc[mm][nn][1] + bv.y;
        float v2 = acc[mm][nn][2] + bv.z;
        float v3 = acc[mm][nn][3] + bv.w;
        if (GELU) {
          v0 = gelu_fast(v0); v1 = gelu_fast(v1);
          v2 = gelu_fast(v2); v3 = gelu_fast(v3);
        }
        OutT* cp = C + ((size_t)e * CAP + token) * M + mrow;
        if constexpr (__is_same(OutT, __hip_bfloat16)) {
          short4v o;
          o[0] = (short)f2bf(v0); o[1] = (short)f2bf(v1);
          o[2] = (short)f2bf(v2); o[3] = (short)f2bf(v3);
          *reinterpret_cast<short4v*>(cp) = o;  // 8B store
        } else {
          float4 o = {v0, v1, v2, v3};
          *reinterpret_cast<float4*>(cp) = o;   // 16B store
        }
      }
    }
  }
}

extern "C" void kernel_launch(void* const* d_in, const int* in_sizes, int n_in,
                              void* d_out, int out_size, void* d_ws, size_t ws_size,
                              hipStream_t stream) {
  const float* x      = (const float*)d_in[0];
  const float* gate_w = (const float*)d_in[1];
  const float* gate_b = (const float*)d_in[2];
  const float* w1     = (const float*)d_in[3];
  const float* b1     = (const float*)d_in[4];
  const float* w2     = (const float*)d_in[5];
  const float* b2     = (const float*)d_in[6];

  float* comb = (float*)d_out;                     // (8,2048,512) f32
  float* gate_probs = comb + (size_t)NTOK * ODIM;  // (16384,8) f32

  // workspace layout (~128.6 MiB)
  char* ws = (char*)d_ws;
  __hip_bfloat16* w1t    = (__hip_bfloat16*)(ws);              // [0,16M)   (E,H,D)
  __hip_bfloat16* w2t    = (__hip_bfloat16*)(ws + 16777216);   // [16,32M)  (E,O,H)
  __hip_bfloat16* hbuf   = (__hip_bfloat16*)(ws + 33554432);   // [32,96M)  (E,CAP,H)
  __hip_bfloat16* xg     = (__hip_bfloat16*)(ws + 100663296);  // [96,112M) (E,CAP,D)
  int*   expert_tokens   = (int*)(ws + 134217728);             // 64 KiB
  int2*  tk_e            = (int2*)(ws + 134283264);            // 128 KiB
  float2* tk_w           = (float2*)(ws + 134414336);          // 128 KiB
  float* slot_w          = (float*)(ws + 134545408);           // 64 KiB

  // comb must start at 0 (GEMM2 scatters into it atomically)
  hipMemsetAsync(comb, 0, (size_t)NTOK * ODIM * sizeof(float), stream);

  // prep: blocks [0,8192) w1-transpose, [8192,16384) w2-transpose, rest gate
  k_prep<<<16384 + NTOK / 4, 256, 0, stream>>>(x, gate_w, gate_b, w1, w1t, w2, w2t,
                                               gate_probs, tk_e, tk_w);
  k_dispatch<<<NE, 1024, 0, stream>>>(tk_e, tk_w, expert_tokens, slot_w);
  k_gather<<<NE * CAP / 4, 256, 0, stream>>>(x, expert_tokens, xg);
  // GEMM1: A=w1t (E,H,D) M=HDIM, B=xg, C=hbuf (E,CAP,H) bf16 + GELU
  k_gemm<DDIM, HDIM, true, false, __hip_bfloat16>
      <<<dim3(CAP / 128, HDIM / 128, NE), 256, 0, stream>>>(
          w1t, xg, b1, hbuf, nullptr, nullptr, nullptr);
  // GEMM2: A=w2t (E,O,H) M=ODIM, B=hbuf; fused combine -> comb (atomicAdd)
  k_gemm<HDIM, ODIM, false, true, float>
      <<<dim3(CAP / 128, ODIM / 128, NE), 256, 0, stream>>>(
          w2t, hbuf, b2, (float*)nullptr, expert_tokens, slot_w, comb);
}

// Round 10
// 167.764 us; speedup vs baseline: 1.5172x; 1.5172x over previous
//
#include <hip/hip_runtime.h>
#include <hip/hip_bf16.h>

// Problem constants (SparseMoE: D=512, H=2048, O=512, E=8, K=2, CF=1.0)
#define NTOK 16384
#define DDIM 512
#define HDIM 2048
#define ODIM 512
#define NE 8
#define CAP 2048   // max(int(N/E*CF), 4) = 2048

typedef __attribute__((ext_vector_type(8))) short short8v;
typedef __attribute__((ext_vector_type(4))) short short4v;
typedef __attribute__((ext_vector_type(8))) unsigned short ushort8v;
typedef __attribute__((ext_vector_type(4))) float f32x4;

static __device__ __forceinline__ unsigned short f2bf(float f) {
  __hip_bfloat16 h = __float2bfloat16(f);
  return __builtin_bit_cast(unsigned short, h);
}
static __device__ __forceinline__ float bf2f(unsigned short u) {
  unsigned int x = ((unsigned int)u) << 16;
  return __builtin_bit_cast(float, x);
}

// async global->LDS, 16B per lane; LDS dest = wave-uniform base + lane*16
#define GLOAD_LDS16(gp, lp)                                               \
  __builtin_amdgcn_global_load_lds(                                       \
      (const __attribute__((address_space(1))) void*)(gp),                \
      (__attribute__((address_space(3))) void*)(lp), 16, 0, 0)

// ---------------- fused prep: transpose w1, transpose w2, gating
__device__ __forceinline__ void transpose_block(const float* __restrict__ src,
                                                __hip_bfloat16* __restrict__ dst,
                                                int R, int C, int b) {
  __shared__ float tile[32][33];
  int nx = C >> 5, ny = R >> 5;
  int x = b % nx, y = (b / nx) % ny, e = b / (nx * ny);
  size_t base = (size_t)e * R * C;
  int c0 = x * 32, r0 = y * 32;
  int tx = threadIdx.x & 31, ty = threadIdx.x >> 5;
#pragma unroll
  for (int i = 0; i < 32; i += 8)
    tile[ty + i][tx] = src[base + (size_t)(r0 + ty + i) * C + c0 + tx];
  __syncthreads();
#pragma unroll
  for (int i = 0; i < 32; i += 8)
    dst[base + (size_t)(c0 + ty + i) * R + r0 + tx] = __float2bfloat16(tile[tx][ty + i]);
}

__global__ void k_prep(const float* __restrict__ x, const float* __restrict__ gw,
                       const float* __restrict__ gb, const float* __restrict__ w1,
                       __hip_bfloat16* __restrict__ w1t, const float* __restrict__ w2,
                       __hip_bfloat16* __restrict__ w2t, float* __restrict__ gate_probs,
                       int2* __restrict__ tk_e, float2* __restrict__ tk_w,
                       int* __restrict__ token_slot) {
  int b = blockIdx.x;
  if (b < 8192) { transpose_block(w1, w1t, DDIM, HDIM, b); return; }
  if (b < 16384) { transpose_block(w2, w2t, HDIM, ODIM, b - 8192); return; }
  b -= 16384;
  __shared__ float gws[DDIM * 9];
  int tid = threadIdx.x;
  for (int i = tid; i < DDIM * NE; i += 256) {
    int d = i >> 3, e = i & 7;
    gws[d * 9 + e] = gw[i];
  }
  __syncthreads();
  int wid = tid >> 6, lane = tid & 63;
  int t = b * 4 + wid;
  const float* xr = x + (size_t)t * DDIM;
  float acc[NE] = {0.f, 0.f, 0.f, 0.f, 0.f, 0.f, 0.f, 0.f};
#pragma unroll
  for (int j = 0; j < 8; ++j) {
    float xv = xr[lane + 64 * j];
    const float* g = &gws[(lane + 64 * j) * 9];
#pragma unroll
    for (int e = 0; e < NE; ++e) acc[e] += xv * g[e];
  }
#pragma unroll
  for (int e = 0; e < NE; ++e) {
#pragma unroll
    for (int off = 32; off > 0; off >>= 1) acc[e] += __shfl_xor(acc[e], off, 64);
  }
  if (lane == 0) {
    float p[NE];
    float m = -1e30f;
#pragma unroll
    for (int e = 0; e < NE; ++e) { p[e] = acc[e] + gb[e]; m = fmaxf(m, p[e]); }
    float s = 0.f;
#pragma unroll
    for (int e = 0; e < NE; ++e) { p[e] = expf(p[e] - m); s += p[e]; }
    float inv = 1.f / s;
#pragma unroll
    for (int e = 0; e < NE; ++e) { p[e] *= inv; gate_probs[(size_t)t * NE + e] = p[e]; }
    int i1 = 0; float p1 = p[0];
#pragma unroll
    for (int e = 1; e < NE; ++e) if (p[e] > p1) { p1 = p[e]; i1 = e; }
    int i2 = -1; float p2 = -1e30f;
#pragma unroll
    for (int e = 0; e < NE; ++e) if (e != i1 && p[e] > p2) { p2 = p[e]; i2 = e; }
    float wsum = p1 + p2;
    tk_e[t] = make_int2(i1, i2);
    tk_w[t] = make_float2(p1 / wsum, p2 / wsum);
    token_slot[2 * t] = -1;
    token_slot[2 * t + 1] = -1;
  }
}

// ---------------- dispatch: per-expert FCFS capacity assignment (block scan)
__global__ void k_dispatch(const int2* __restrict__ tk_e, int* __restrict__ token_slot,
                           int* __restrict__ expert_tokens) {
  int e = blockIdx.x;
  int tid = threadIdx.x;
  int lane = tid & 63, w = tid >> 6;   // 16 waves
  __shared__ int wave_cnt[16];
  int base = 0;
  for (int chunk = 0; chunk < NTOK / 1024; ++chunk) {
    int t = chunk * 1024 + tid;
    int2 te = tk_e[t];
    int k = (te.x == e) ? 0 : ((te.y == e) ? 1 : -1);
    bool flag = (k >= 0);
    unsigned long long m = __ballot(flag);
    int pre = __popcll(m & ((1ull << lane) - 1ull));
    __syncthreads();
    if (lane == 0) wave_cnt[w] = __popcll(m);
    __syncthreads();
    int off = 0, total = 0;
#pragma unroll
    for (int i = 0; i < 16; ++i) {
      off += (i < w) ? wave_cnt[i] : 0;
      total += wave_cnt[i];
    }
    int rank = base + off + pre;
    if (flag && rank < CAP) {
      expert_tokens[e * CAP + rank] = t;
      token_slot[2 * t + k] = e * CAP + rank;
    }
    base += total;
  }
  int nvalid = base < CAP ? base : CAP;
  for (int s = nvalid + tid; s < CAP; s += 1024)
    expert_tokens[e * CAP + s] = 0;  // padded slots: weight 0, never combined
}

// ---------------- gather: xg[e][c][:] = bf16(x[expert_tokens[e*CAP+c]][:])
__global__ void k_gather(const float* __restrict__ x,
                         const int* __restrict__ expert_tokens,
                         __hip_bfloat16* __restrict__ xg) {
  int tid = threadIdx.x, wid = tid >> 6, lane = tid & 63;
  int slot = blockIdx.x * 4 + wid;  // 0..E*CAP-1
  int tok = expert_tokens[slot];
  const float4* src = reinterpret_cast<const float4*>(x + (size_t)tok * DDIM) + lane * 2;
  float4 u = src[0], v = src[1];
  ushort8v o;
  o[0] = f2bf(u.x); o[1] = f2bf(u.y); o[2] = f2bf(u.z); o[3] = f2bf(u.w);
  o[4] = f2bf(v.x); o[5] = f2bf(v.y); o[6] = f2bf(v.z); o[7] = f2bf(v.w);
  *reinterpret_cast<ushort8v*>(xg + (size_t)slot * DDIM + lane * 8) = o;
}

// sigmoid-form tanh-GELU: |err vs exact erf-gelu| < ~1e-3, safe for bf16 out
static __device__ __forceinline__ float gelu_fast(float v) {
  float z = 1.5957691216057308f * (v + 0.044715f * v * v * v);
  return v / (1.f + __expf(-z));
}

// ---------------- pipelined GEMM (r5 best-measured: ~62 us/GEMM):
// 128x128 tile, BK=32, 3 LDS buffers, register ping-pong fragments.
// Per K-step (ONE barrier): counted vmcnt -> barrier -> ds_read next frags
// -> stage t+3 -> sched_barrier -> MFMA cur -> lgkmcnt(0)+sched_barrier.
// A = weights (E, M, K); B = tokens (E, CAP, K); C = (E, CAP, M).
template <int K, int M, bool GELU, typename OutT>
__global__ __launch_bounds__(256, 3) void k_gemm(
    const __hip_bfloat16* __restrict__ A, const __hip_bfloat16* __restrict__ B,
    const float* __restrict__ bias, OutT* __restrict__ C) {
  __shared__ char lds[3][16384];  // [buf][ A:8KB | B:8KB ], 48 KB total
  // XCD-aware bijective remap (grid total is a multiple of 8)
  int gx = gridDim.x, gy = gridDim.y;
  int lin = (blockIdx.z * gy + blockIdx.y) * gx + blockIdx.x;
  int total = gx * gy * (int)gridDim.z;
  int cpx = total >> 3;
  lin = (lin & 7) * cpx + (lin >> 3);
  int gxy = gx * gy;
  int e = lin / gxy;
  int rem = lin - e * gxy;
  int mt = rem / gx, nt = rem - mt * gx;

  const int m0 = mt * 128, n0 = nt * 128;
  const int tid = threadIdx.x;
  const int lane = tid & 63, wid = tid >> 6;
  const int wr = wid >> 1, wc = wid & 1;
  const int lrow = lane & 15, kseg = lane >> 4;

  const int r0 = tid >> 2;                     // staging row 0..63
  const int sc = (tid & 3) ^ ((r0 >> 1) & 3);  // inverse-swizzled source k16
  const int cb0 = (tid & 192) * 16;            // wave-uniform LDS byte base
  const int cb1 = 4096 + cb0;
  const __hip_bfloat16* Ab = A + ((size_t)e * M + m0) * K;
  const __hip_bfloat16* Bb = B + ((size_t)e * CAP + n0) * K;

#define STAGE(buf, kk)                                                         \
  do {                                                                         \
    GLOAD_LDS16(Ab + (size_t)r0 * K + (kk) + sc * 8, lds[buf] + cb0);          \
    GLOAD_LDS16(Ab + (size_t)(r0 + 64) * K + (kk) + sc * 8, lds[buf] + cb1);   \
    GLOAD_LDS16(Bb + (size_t)r0 * K + (kk) + sc * 8, lds[buf] + 8192 + cb0);   \
    GLOAD_LDS16(Bb + (size_t)(r0 + 64) * K + (kk) + sc * 8, lds[buf] + 8192 + cb1); \
  } while (0)

#define READF(fa, fb, bi)                                                      \
  do {                                                                         \
    const char* AsB_ = lds[bi];                                                \
    const char* BsB_ = lds[bi] + 8192;                                         \
    _Pragma("unroll")                                                          \
    for (int mm = 0; mm < 4; ++mm) {                                           \
      int rr = wr * 64 + mm * 16 + lrow;                                       \
      int ks = kseg ^ ((rr >> 1) & 3);                                         \
      fa[mm] = *reinterpret_cast<const short8v*>(AsB_ + rr * 64 + ks * 16);    \
    }                                                                          \
    _Pragma("unroll")                                                          \
    for (int nn = 0; nn < 4; ++nn) {                                           \
      int rr = wc * 64 + nn * 16 + lrow;                                       \
      int ks = kseg ^ ((rr >> 1) & 3);                                         \
      fb[nn] = *reinterpret_cast<const short8v*>(BsB_ + rr * 64 + ks * 16);    \
    }                                                                          \
  } while (0)

#define MFMA16(fa, fb)                                                         \
  do {                                                                         \
    __builtin_amdgcn_s_setprio(1);                                             \
    _Pragma("unroll")                                                          \
    for (int mm = 0; mm < 4; ++mm)                                             \
      _Pragma("unroll")                                                        \
      for (int nn = 0; nn < 4; ++nn)                                           \
        acc[mm][nn] = __builtin_amdgcn_mfma_f32_16x16x32_bf16(                 \
            fa[mm], fb[nn], acc[mm][nn], 0, 0, 0);                             \
    __builtin_amdgcn_s_setprio(0);                                             \
  } while (0)

#define LGKM0_FENCE()                                                          \
  do {                                                                         \
    asm volatile("s_waitcnt lgkmcnt(0)" ::: "memory");                         \
    __builtin_amdgcn_sched_barrier(0);                                         \
  } while (0)

  f32x4 acc[4][4] = {};
  short8v pa[4], pb[4], qa[4], qb[4];  // ping / pong fragment sets
  const int T = K >> 5;                // K-tiles: 16 (GEMM1) or 64 (GEMM2)

  STAGE(0, 0);
  STAGE(1, 32);
  STAGE(2, 64);
  asm volatile("s_waitcnt vmcnt(8)" ::: "memory");  // tile 0 resident
  __builtin_amdgcn_s_barrier();
  READF(pa, pb, 0);
  LGKM0_FENCE();

  int bt = 0;  // t % 3
  for (int t = 0; t < T; t += 2) {
    int b1 = (bt == 2) ? 0 : bt + 1;  // (t+1) % 3
    int b2 = (b1 == 2) ? 0 : b1 + 1;  // (t+2) % 3
    // ---- even step: make tile t+1 visible, read->pong, MFMA ping
    if (t + 2 < T) asm volatile("s_waitcnt vmcnt(4)" ::: "memory");
    else           asm volatile("s_waitcnt vmcnt(0)" ::: "memory");
    __builtin_amdgcn_s_barrier();
    READF(qa, qb, b1);
    if (t + 3 < T) STAGE(bt, (t + 3) * 32);
    __builtin_amdgcn_sched_barrier(0);  // reads+stage issue before MFMA
    MFMA16(pa, pb);
    LGKM0_FENCE();                      // pong landed; fence next MFMA
    // ---- odd step: make tile t+2 visible, read->ping, MFMA pong
    if (t + 2 < T) {
      if (t + 3 < T) asm volatile("s_waitcnt vmcnt(4)" ::: "memory");
      else           asm volatile("s_waitcnt vmcnt(0)" ::: "memory");
      __builtin_amdgcn_s_barrier();
      READF(pa, pb, b2);
      if (t + 4 < T) STAGE(b1, (t + 4) * 32);
      __builtin_amdgcn_sched_barrier(0);
    }
    MFMA16(qa, qb);
    LGKM0_FENCE();
    bt = b2;
  }
#undef STAGE
#undef READF
#undef MFMA16
#undef LGKM0_FENCE

  // epilogue: lane holds 4 consecutive output-features (rows of A) at one token
#pragma unroll
  for (int mm = 0; mm < 4; ++mm) {
    int mrow = m0 + wr * 64 + mm * 16 + kseg * 4;
    float4 bv = *reinterpret_cast<const float4*>(&bias[e * M + mrow]);
#pragma unroll
    for (int nn = 0; nn < 4; ++nn) {
      int token = n0 + wc * 64 + nn * 16 + lrow;
      float v0 = acc[mm][nn][0] + bv.x;
      float v1 = acc[mm][nn][1] + bv.y;
      float v2 = acc[mm][nn][2] + bv.z;
      float v3 = acc[mm][nn][3] + bv.w;
      if (GELU) {
        v0 = gelu_fast(v0); v1 = gelu_fast(v1);
        v2 = gelu_fast(v2); v3 = gelu_fast(v3);
      }
      OutT* cp = C + ((size_t)e * CAP + token) * M + mrow;
      if constexpr (__is_same(OutT, __hip_bfloat16)) {
        short4v o;
        o[0] = (short)f2bf(v0); o[1] = (short)f2bf(v1);
        o[2] = (short)f2bf(v2); o[3] = (short)f2bf(v3);
        *reinterpret_cast<short4v*>(cp) = o;  // 8B store
      } else {
        float4 o = {v0, v1, v2, v3};
        *reinterpret_cast<float4*>(cp) = o;   // 16B store
      }
    }
  }
}

// ---------------- combine: per token, sum its <=2 weighted expert rows (bf16 in)
__global__ void k_combine(const __hip_bfloat16* __restrict__ outbuf,
                          const int* __restrict__ token_slot,
                          const float2* __restrict__ tk_w,
                          float* __restrict__ comb) {
  int tid = threadIdx.x;
  int wid = tid >> 6, lane = tid & 63;
  int t = blockIdx.x * 4 + wid;
  int s0 = token_slot[2 * t], s1 = token_slot[2 * t + 1];
  float2 w = tk_w[t];
  float r[8] = {0.f, 0.f, 0.f, 0.f, 0.f, 0.f, 0.f, 0.f};
  if (s0 >= 0) {
    ushort8v a = *reinterpret_cast<const ushort8v*>(outbuf + (size_t)s0 * ODIM + lane * 8);
#pragma unroll
    for (int j = 0; j < 8; ++j) r[j] += w.x * bf2f(a[j]);
  }
  if (s1 >= 0) {
    ushort8v a = *reinterpret_cast<const ushort8v*>(outbuf + (size_t)s1 * ODIM + lane * 8);
#pragma unroll
    for (int j = 0; j < 8; ++j) r[j] += w.y * bf2f(a[j]);
  }
  float4* q = reinterpret_cast<float4*>(comb + (size_t)t * ODIM + lane * 8);
  float4 o0 = {r[0], r[1], r[2], r[3]};
  float4 o1 = {r[4], r[5], r[6], r[7]};
  q[0] = o0;
  q[1] = o1;
}

extern "C" void kernel_launch(void* const* d_in, const int* in_sizes, int n_in,
                              void* d_out, int out_size, void* d_ws, size_t ws_size,
                              hipStream_t stream) {
  const float* x      = (const float*)d_in[0];
  const float* gate_w = (const float*)d_in[1];
  const float* gate_b = (const float*)d_in[2];
  const float* w1     = (const float*)d_in[3];
  const float* b1     = (const float*)d_in[4];
  const float* w2     = (const float*)d_in[5];
  const float* b2     = (const float*)d_in[6];

  float* comb = (float*)d_out;                     // (8,2048,512) f32
  float* gate_probs = comb + (size_t)NTOK * ODIM;  // (16384,8) f32

  // workspace layout (~128.6 MiB)
  char* ws = (char*)d_ws;
  __hip_bfloat16* w1t    = (__hip_bfloat16*)(ws);              // [0,16M)   (E,H,D)
  __hip_bfloat16* w2t    = (__hip_bfloat16*)(ws + 16777216);   // [16,32M)  (E,O,H)
  __hip_bfloat16* hbuf   = (__hip_bfloat16*)(ws + 33554432);   // [32,96M)  (E,CAP,H)
  __hip_bfloat16* xg     = (__hip_bfloat16*)(ws + 100663296);  // [96,112M) (E,CAP,D)
  __hip_bfloat16* outbuf = (__hip_bfloat16*)(ws + 117440512);  // [112,128M)(E,CAP,O) bf16
  int*   expert_tokens   = (int*)(ws + 134217728);             // 64 KiB
  int2*  tk_e            = (int2*)(ws + 134283264);            // 128 KiB
  float2* tk_w           = (float2*)(ws + 134414336);          // 128 KiB
  int*   token_slot      = (int*)(ws + 134545408);             // 128 KiB

  // prep: blocks [0,8192) w1-transpose, [8192,16384) w2-transpose, rest gate
  k_prep<<<16384 + NTOK / 4, 256, 0, stream>>>(x, gate_w, gate_b, w1, w1t, w2, w2t,
                                               gate_probs, tk_e, tk_w, token_slot);
  k_dispatch<<<NE, 1024, 0, stream>>>(tk_e, token_slot, expert_tokens);
  k_gather<<<NE * CAP / 4, 256, 0, stream>>>(x, expert_tokens, xg);
  // GEMM1: A=w1t (E,H,D) M=HDIM, B=xg, C=hbuf (E,CAP,H) bf16 + GELU
  k_gemm<DDIM, HDIM, true, __hip_bfloat16>
      <<<dim3(CAP / 128, HDIM / 128, NE), 256, 0, stream>>>(w1t, xg, b1, hbuf);
  // GEMM2: A=w2t (E,O,H) M=ODIM, B=hbuf, C=outbuf (E,CAP,O) bf16
  k_gemm<HDIM, ODIM, false, __hip_bfloat16>
      <<<dim3(CAP / 128, ODIM / 128, NE), 256, 0, stream>>>(w2t, hbuf, b2, outbuf);
  k_combine<<<NTOK / 4, 256, 0, stream>>>(outbuf, token_slot, tk_w, comb);
}

// Round 11
// 160.005 us; speedup vs baseline: 1.5908x; 1.0485x over previous
//
#include <hip/hip_runtime.h>
#include <hip/hip_bf16.h>

// Problem constants (SparseMoE: D=512, H=2048, O=512, E=8, K=2, CF=1.0)
#define NTOK 16384
#define DDIM 512
#define HDIM 2048
#define ODIM 512
#define NE 8
#define CAP 2048   // max(int(N/E*CF), 4) = 2048

typedef __attribute__((ext_vector_type(8))) short short8v;
typedef __attribute__((ext_vector_type(4))) short short4v;
typedef __attribute__((ext_vector_type(8))) unsigned short ushort8v;
typedef __attribute__((ext_vector_type(4))) float f32x4;

static __device__ __forceinline__ unsigned short f2bf(float f) {
  __hip_bfloat16 h = __float2bfloat16(f);
  return __builtin_bit_cast(unsigned short, h);
}
static __device__ __forceinline__ float bf2f(unsigned short u) {
  unsigned int x = ((unsigned int)u) << 16;
  return __builtin_bit_cast(float, x);
}

// async global->LDS, 16B per lane; LDS dest = wave-uniform base + lane*16
#define GLOAD_LDS16(gp, lp)                                               \
  __builtin_amdgcn_global_load_lds(                                       \
      (const __attribute__((address_space(1))) void*)(gp),                \
      (__attribute__((address_space(3))) void*)(lp), 16, 0, 0)

// ---------------- fused prep: transpose w1, transpose w2, gating (+ x->bf16)
__device__ __forceinline__ void transpose_block(const float* __restrict__ src,
                                                __hip_bfloat16* __restrict__ dst,
                                                int R, int C, int b) {
  __shared__ float tile[32][33];
  int nx = C >> 5, ny = R >> 5;
  int x = b % nx, y = (b / nx) % ny, e = b / (nx * ny);
  size_t base = (size_t)e * R * C;
  int c0 = x * 32, r0 = y * 32;
  int tx = threadIdx.x & 31, ty = threadIdx.x >> 5;
#pragma unroll
  for (int i = 0; i < 32; i += 8)
    tile[ty + i][tx] = src[base + (size_t)(r0 + ty + i) * C + c0 + tx];
  __syncthreads();
#pragma unroll
  for (int i = 0; i < 32; i += 8)
    dst[base + (size_t)(c0 + ty + i) * R + r0 + tx] = __float2bfloat16(tile[tx][ty + i]);
}

__global__ void k_prep(const float* __restrict__ x, const float* __restrict__ gw,
                       const float* __restrict__ gb, const float* __restrict__ w1,
                       __hip_bfloat16* __restrict__ w1t, const float* __restrict__ w2,
                       __hip_bfloat16* __restrict__ w2t, float* __restrict__ gate_probs,
                       int2* __restrict__ tk_e, float2* __restrict__ tk_w,
                       int* __restrict__ token_slot, __hip_bfloat16* __restrict__ xbf) {
  int b = blockIdx.x;
  if (b < 8192) { transpose_block(w1, w1t, DDIM, HDIM, b); return; }
  if (b < 16384) { transpose_block(w2, w2t, HDIM, ODIM, b - 8192); return; }
  b -= 16384;
  __shared__ float gws[DDIM * 9];
  int tid = threadIdx.x;
  for (int i = tid; i < DDIM * NE; i += 256) {
    int d = i >> 3, e = i & 7;
    gws[d * 9 + e] = gw[i];
  }
  __syncthreads();
  int wid = tid >> 6, lane = tid & 63;
  int t = b * 4 + wid;
  const float* xr = x + (size_t)t * DDIM;
  float acc[NE] = {0.f, 0.f, 0.f, 0.f, 0.f, 0.f, 0.f, 0.f};
  float xv[8];
#pragma unroll
  for (int j = 0; j < 8; ++j) {
    xv[j] = xr[lane + 64 * j];
    const float* g = &gws[(lane + 64 * j) * 9];
#pragma unroll
    for (int e = 0; e < NE; ++e) acc[e] += xv[j] * g[e];
  }
  // write x in bf16 (coalesced 128B per wave per j)
  __hip_bfloat16* xb = xbf + (size_t)t * DDIM + lane;
#pragma unroll
  for (int j = 0; j < 8; ++j) xb[64 * j] = __float2bfloat16(xv[j]);
#pragma unroll
  for (int e = 0; e < NE; ++e) {
#pragma unroll
    for (int off = 32; off > 0; off >>= 1) acc[e] += __shfl_xor(acc[e], off, 64);
  }
  if (lane == 0) {
    float p[NE];
    float m = -1e30f;
#pragma unroll
    for (int e = 0; e < NE; ++e) { p[e] = acc[e] + gb[e]; m = fmaxf(m, p[e]); }
    float s = 0.f;
#pragma unroll
    for (int e = 0; e < NE; ++e) { p[e] = expf(p[e] - m); s += p[e]; }
    float inv = 1.f / s;
#pragma unroll
    for (int e = 0; e < NE; ++e) { p[e] *= inv; gate_probs[(size_t)t * NE + e] = p[e]; }
    int i1 = 0; float p1 = p[0];
#pragma unroll
    for (int e = 1; e < NE; ++e) if (p[e] > p1) { p1 = p[e]; i1 = e; }
    int i2 = -1; float p2 = -1e30f;
#pragma unroll
    for (int e = 0; e < NE; ++e) if (e != i1 && p[e] > p2) { p2 = p[e]; i2 = e; }
    float wsum = p1 + p2;
    tk_e[t] = make_int2(i1, i2);
    tk_w[t] = make_float2(p1 / wsum, p2 / wsum);
    token_slot[2 * t] = -1;
    token_slot[2 * t + 1] = -1;
  }
}

// ---------------- dispatch: per-expert FCFS capacity assignment (block scan)
__global__ void k_dispatch(const int2* __restrict__ tk_e, int* __restrict__ token_slot,
                           int* __restrict__ expert_tokens) {
  int e = blockIdx.x;
  int tid = threadIdx.x;
  int lane = tid & 63, w = tid >> 6;   // 16 waves
  __shared__ int wave_cnt[16];
  int base = 0;
  for (int chunk = 0; chunk < NTOK / 1024; ++chunk) {
    int t = chunk * 1024 + tid;
    int2 te = tk_e[t];
    int k = (te.x == e) ? 0 : ((te.y == e) ? 1 : -1);
    bool flag = (k >= 0);
    unsigned long long m = __ballot(flag);
    int pre = __popcll(m & ((1ull << lane) - 1ull));
    __syncthreads();
    if (lane == 0) wave_cnt[w] = __popcll(m);
    __syncthreads();
    int off = 0, total = 0;
#pragma unroll
    for (int i = 0; i < 16; ++i) {
      off += (i < w) ? wave_cnt[i] : 0;
      total += wave_cnt[i];
    }
    int rank = base + off + pre;
    if (flag && rank < CAP) {
      expert_tokens[e * CAP + rank] = t;
      token_slot[2 * t + k] = e * CAP + rank;
    }
    base += total;
  }
  int nvalid = base < CAP ? base : CAP;
  for (int s = nvalid + tid; s < CAP; s += 1024)
    expert_tokens[e * CAP + s] = 0;  // padded slots: weight 0, never combined
}

// sigmoid-form tanh-GELU: |err vs exact erf-gelu| < ~1e-3, safe for bf16 out
static __device__ __forceinline__ float gelu_fast(float v) {
  float z = 1.5957691216057308f * (v + 0.044715f * v * v * v);
  return v / (1.f + __expf(-z));
}

// ---------------- pipelined GEMM (r5 structure + full unroll + opt. indirect B):
// 128x128 tile, BK=32, 3 LDS buffers, register ping-pong fragments, counted
// vmcnt. K-loop FULLY UNROLLED (T template-const) -> buffer indices and all
// ds_read/gload addresses const-fold (cuts the measured 38% VALUBusy).
// INDIR: B rows come from xbf via expert_tokens (gather fused into staging).
template <int K, int M, bool GELU, bool INDIR, typename OutT>
__global__ __launch_bounds__(256, 3) void k_gemm(
    const __hip_bfloat16* __restrict__ A, const __hip_bfloat16* __restrict__ B,
    const float* __restrict__ bias, OutT* __restrict__ C,
    const int* __restrict__ etok) {
  __shared__ char lds[3][16384];  // [buf][ A:8KB | B:8KB ], 48 KB total
  // XCD-aware bijective remap (grid total is a multiple of 8)
  int gx = gridDim.x, gy = gridDim.y;
  int lin = (blockIdx.z * gy + blockIdx.y) * gx + blockIdx.x;
  int total = gx * gy * (int)gridDim.z;
  int cpx = total >> 3;
  lin = (lin & 7) * cpx + (lin >> 3);
  int gxy = gx * gy;
  int e = lin / gxy;
  int rem = lin - e * gxy;
  int mt = rem / gx, nt = rem - mt * gx;

  const int m0 = mt * 128, n0 = nt * 128;
  const int tid = threadIdx.x;
  const int lane = tid & 63, wid = tid >> 6;
  const int wr = wid >> 1, wc = wid & 1;
  const int lrow = lane & 15, kseg = lane >> 4;

  const int r0 = tid >> 2;                     // staging row 0..63
  const int sc = (tid & 3) ^ ((r0 >> 1) & 3);  // inverse-swizzled source k16
  const int cb0 = (tid & 192) * 16;            // wave-uniform LDS byte base
  const int cb1 = 4096 + cb0;
  const __hip_bfloat16* Ap0 = A + ((size_t)e * M + m0 + r0) * K + sc * 8;
  const __hip_bfloat16* Ap1 = Ap0 + (size_t)64 * K;
  const __hip_bfloat16* Bp0;
  const __hip_bfloat16* Bp1;
  if constexpr (INDIR) {
    int t0 = etok[e * CAP + n0 + r0];
    int t1 = etok[e * CAP + n0 + r0 + 64];
    Bp0 = B + (size_t)t0 * K + sc * 8;   // B = xbf (token-major), K == DDIM
    Bp1 = B + (size_t)t1 * K + sc * 8;
  } else {
    Bp0 = B + ((size_t)e * CAP + n0 + r0) * K + sc * 8;
    Bp1 = Bp0 + (size_t)64 * K;
  }

#define STAGE(buf, kk)                                                         \
  do {                                                                         \
    GLOAD_LDS16(Ap0 + (kk), lds[buf] + cb0);                                   \
    GLOAD_LDS16(Ap1 + (kk), lds[buf] + cb1);                                   \
    GLOAD_LDS16(Bp0 + (kk), lds[buf] + 8192 + cb0);                            \
    GLOAD_LDS16(Bp1 + (kk), lds[buf] + 8192 + cb1);                            \
  } while (0)

#define READF(fa, fb, bi)                                                      \
  do {                                                                         \
    const char* AsB_ = lds[bi];                                                \
    const char* BsB_ = lds[bi] + 8192;                                         \
    _Pragma("unroll")                                                          \
    for (int mm = 0; mm < 4; ++mm) {                                           \
      int rr = wr * 64 + mm * 16 + lrow;                                       \
      int ks = kseg ^ ((rr >> 1) & 3);                                         \
      fa[mm] = *reinterpret_cast<const short8v*>(AsB_ + rr * 64 + ks * 16);    \
    }                                                                          \
    _Pragma("unroll")                                                          \
    for (int nn = 0; nn < 4; ++nn) {                                           \
      int rr = wc * 64 + nn * 16 + lrow;                                       \
      int ks = kseg ^ ((rr >> 1) & 3);                                         \
      fb[nn] = *reinterpret_cast<const short8v*>(BsB_ + rr * 64 + ks * 16);    \
    }                                                                          \
  } while (0)

#define MFMA16(fa, fb)                                                         \
  do {                                                                         \
    __builtin_amdgcn_s_setprio(1);                                             \
    _Pragma("unroll")                                                          \
    for (int mm = 0; mm < 4; ++mm)                                             \
      _Pragma("unroll")                                                        \
      for (int nn = 0; nn < 4; ++nn)                                           \
        acc[mm][nn] = __builtin_amdgcn_mfma_f32_16x16x32_bf16(                 \
            fa[mm], fb[nn], acc[mm][nn], 0, 0, 0);                             \
    __builtin_amdgcn_s_setprio(0);                                             \
  } while (0)

#define LGKM0_FENCE()                                                          \
  do {                                                                         \
    asm volatile("s_waitcnt lgkmcnt(0)" ::: "memory");                         \
    __builtin_amdgcn_sched_barrier(0);                                         \
  } while (0)

  f32x4 acc[4][4] = {};
  short8v pa[4], pb[4], qa[4], qb[4];  // ping / pong fragment sets
  constexpr int T = K >> 5;            // K-tiles: 16 (GEMM1) or 64 (GEMM2)

  STAGE(0, 0);
  STAGE(1, 32);
  STAGE(2, 64);
  asm volatile("s_waitcnt vmcnt(8)" ::: "memory");  // tile 0 resident
  __builtin_amdgcn_s_barrier();
  READF(pa, pb, 0);
  LGKM0_FENCE();

#pragma unroll
  for (int t = 0; t < T; t += 2) {
    const int bt = t % 3;        // const after full unroll
    const int b1 = (t + 1) % 3;
    const int b2 = (t + 2) % 3;
    // ---- even step: make tile t+1 visible, read->pong, MFMA ping
    if (t + 2 < T) asm volatile("s_waitcnt vmcnt(4)" ::: "memory");
    else           asm volatile("s_waitcnt vmcnt(0)" ::: "memory");
    __builtin_amdgcn_s_barrier();
    READF(qa, qb, b1);
    if (t + 3 < T) STAGE(bt, (t + 3) * 32);
    __builtin_amdgcn_sched_barrier(0);  // reads+stage issue before MFMA
    MFMA16(pa, pb);
    LGKM0_FENCE();                      // pong landed; fence next MFMA
    // ---- odd step: make tile t+2 visible, read->ping, MFMA pong
    if (t + 2 < T) {
      if (t + 3 < T) asm volatile("s_waitcnt vmcnt(4)" ::: "memory");
      else           asm volatile("s_waitcnt vmcnt(0)" ::: "memory");
      __builtin_amdgcn_s_barrier();
      READF(pa, pb, b2);
      if (t + 4 < T) STAGE(b1, (t + 4) * 32);
      __builtin_amdgcn_sched_barrier(0);
    }
    MFMA16(qa, qb);
    LGKM0_FENCE();
  }
#undef STAGE
#undef READF
#undef MFMA16
#undef LGKM0_FENCE

  // epilogue: lane holds 4 consecutive output-features (rows of A) at one token
#pragma unroll
  for (int mm = 0; mm < 4; ++mm) {
    int mrow = m0 + wr * 64 + mm * 16 + kseg * 4;
    float4 bv = *reinterpret_cast<const float4*>(&bias[e * M + mrow]);
#pragma unroll
    for (int nn = 0; nn < 4; ++nn) {
      int token = n0 + wc * 64 + nn * 16 + lrow;
      float v0 = acc[mm][nn][0] + bv.x;
      float v1 = acc[mm][nn][1] + bv.y;
      float v2 = acc[mm][nn][2] + bv.z;
      float v3 = acc[mm][nn][3] + bv.w;
      if (GELU) {
        v0 = gelu_fast(v0); v1 = gelu_fast(v1);
        v2 = gelu_fast(v2); v3 = gelu_fast(v3);
      }
      OutT* cp = C + ((size_t)e * CAP + token) * M + mrow;
      if constexpr (__is_same(OutT, __hip_bfloat16)) {
        short4v o;
        o[0] = (short)f2bf(v0); o[1] = (short)f2bf(v1);
        o[2] = (short)f2bf(v2); o[3] = (short)f2bf(v3);
        *reinterpret_cast<short4v*>(cp) = o;  // 8B store
      } else {
        float4 o = {v0, v1, v2, v3};
        *reinterpret_cast<float4*>(cp) = o;   // 16B store
      }
    }
  }
}

// ---------------- combine: per token, sum its <=2 weighted expert rows (bf16 in)
__global__ void k_combine(const __hip_bfloat16* __restrict__ outbuf,
                          const int* __restrict__ token_slot,
                          const float2* __restrict__ tk_w,
                          float* __restrict__ comb) {
  int tid = threadIdx.x;
  int wid = tid >> 6, lane = tid & 63;
  int t = blockIdx.x * 4 + wid;
  int s0 = token_slot[2 * t], s1 = token_slot[2 * t + 1];
  float2 w = tk_w[t];
  float r[8] = {0.f, 0.f, 0.f, 0.f, 0.f, 0.f, 0.f, 0.f};
  if (s0 >= 0) {
    ushort8v a = *reinterpret_cast<const ushort8v*>(outbuf + (size_t)s0 * ODIM + lane * 8);
#pragma unroll
    for (int j = 0; j < 8; ++j) r[j] += w.x * bf2f(a[j]);
  }
  if (s1 >= 0) {
    ushort8v a = *reinterpret_cast<const ushort8v*>(outbuf + (size_t)s1 * ODIM + lane * 8);
#pragma unroll
    for (int j = 0; j < 8; ++j) r[j] += w.y * bf2f(a[j]);
  }
  float4* q = reinterpret_cast<float4*>(comb + (size_t)t * ODIM + lane * 8);
  float4 o0 = {r[0], r[1], r[2], r[3]};
  float4 o1 = {r[4], r[5], r[6], r[7]};
  q[0] = o0;
  q[1] = o1;
}

extern "C" void kernel_launch(void* const* d_in, const int* in_sizes, int n_in,
                              void* d_out, int out_size, void* d_ws, size_t ws_size,
                              hipStream_t stream) {
  const float* x      = (const float*)d_in[0];
  const float* gate_w = (const float*)d_in[1];
  const float* gate_b = (const float*)d_in[2];
  const float* w1     = (const float*)d_in[3];
  const float* b1     = (const float*)d_in[4];
  const float* w2     = (const float*)d_in[5];
  const float* b2     = (const float*)d_in[6];

  float* comb = (float*)d_out;                     // (8,2048,512) f32
  float* gate_probs = comb + (size_t)NTOK * ODIM;  // (16384,8) f32

  // workspace layout (~128.6 MiB)
  char* ws = (char*)d_ws;
  __hip_bfloat16* w1t    = (__hip_bfloat16*)(ws);              // [0,16M)   (E,H,D)
  __hip_bfloat16* w2t    = (__hip_bfloat16*)(ws + 16777216);   // [16,32M)  (E,O,H)
  __hip_bfloat16* hbuf   = (__hip_bfloat16*)(ws + 33554432);   // [32,96M)  (E,CAP,H)
  __hip_bfloat16* xbf    = (__hip_bfloat16*)(ws + 100663296);  // [96,112M) (NTOK,D) bf16
  __hip_bfloat16* outbuf = (__hip_bfloat16*)(ws + 117440512);  // [112,128M)(E,CAP,O) bf16
  int*   expert_tokens   = (int*)(ws + 134217728);             // 64 KiB
  int2*  tk_e            = (int2*)(ws + 134283264);            // 128 KiB
  float2* tk_w           = (float2*)(ws + 134414336);          // 128 KiB
  int*   token_slot      = (int*)(ws + 134545408);             // 128 KiB

  // prep: blocks [0,8192) w1-transpose, [8192,16384) w2-transpose, rest gate+xbf
  k_prep<<<16384 + NTOK / 4, 256, 0, stream>>>(x, gate_w, gate_b, w1, w1t, w2, w2t,
                                               gate_probs, tk_e, tk_w, token_slot, xbf);
  k_dispatch<<<NE, 1024, 0, stream>>>(tk_e, token_slot, expert_tokens);
  // GEMM1: A=w1t (E,H,D) M=HDIM, B=xbf via expert_tokens (indirect), GELU
  k_gemm<DDIM, HDIM, true, true, __hip_bfloat16>
      <<<dim3(CAP / 128, HDIM / 128, NE), 256, 0, stream>>>(
          w1t, xbf, b1, hbuf, expert_tokens);
  // GEMM2: A=w2t (E,O,H) M=ODIM, B=hbuf, C=outbuf (E,CAP,O) bf16
  k_gemm<HDIM, ODIM, false, false, __hip_bfloat16>
      <<<dim3(CAP / 128, ODIM / 128, NE), 256, 0, stream>>>(
          w2t, hbuf, b2, outbuf, nullptr);
  k_combine<<<NTOK / 4, 256, 0, stream>>>(outbuf, token_slot, tk_w, comb);
}